// Round 6
// baseline (151.468 us; speedup 1.0000x reference)
//
#include <hip/hip_runtime.h>
#include <stdint.h>

#define B_ 4
#define T_ 2048
#define C_ 1024
#define H_ 128
#define NEG_BIG -3.0e38f

typedef __attribute__((ext_vector_type(8))) short short8;
typedef __attribute__((ext_vector_type(4))) float f32x4;
typedef __attribute__((ext_vector_type(4))) unsigned short ushort4v;
typedef __attribute__((ext_vector_type(8))) unsigned short ushort8v;

// cheap bf16 cast: round-half-up, <=0.5 ULP (inputs are finite randn-scale)
__device__ __forceinline__ unsigned short f2bf(float f) {
  union { float f; unsigned u; } cv; cv.f = f;
  return (unsigned short)((cv.u + 0x8000u) >> 16);
}

__device__ __forceinline__ float bf2f(unsigned short s) {
  union { unsigned u; float f; } cv; cv.u = ((unsigned)s) << 16;
  return cv.f;
}

// async global->LDS, 16 bytes per lane. LDS dest = wave-uniform base + lane*16.
__device__ __forceinline__ void gld16(const void* g, void* l) {
  __builtin_amdgcn_global_load_lds(
      (const __attribute__((address_space(1))) unsigned int*)g,
      (__attribute__((address_space(3))) unsigned int*)l, 16, 0, 0);
}

// scale = C^-0.5 = 1/32; folded with log2(e) for exp2-domain softmax
#define CSCALE 0.045084220027780106f

// ---------------------------------------------------------------------------
// Kernel 1: prep_w — cast Wq|Wk|Wv (fp32 [1024][128]) to WbT bf16 [384][1024]
// (transposed so B-fragments are contiguous). Tiny: 1.5 MB read, 768 KB write.
// ---------------------------------------------------------------------------
__global__ __launch_bounds__(256) void prep_w(const float* __restrict__ Wq,
                                              const float* __restrict__ Wk,
                                              const float* __restrict__ Wv,
                                              unsigned short* __restrict__ WbT) {
  const int i = blockIdx.x * 256 + threadIdx.x;   // 0..98303
  const int linear = i * 4;                       // < 393216
  const int j = linear >> 10;                     // output row 0..383
  const int k0 = linear & 1023;
  const float* W = (j < 128) ? Wq : (j < 256) ? Wk : Wv;
  const int h = j & 127;
  ushort4v p;
  p[0] = f2bf(W[(k0 + 0) * 128 + h]);
  p[1] = f2bf(W[(k0 + 1) * 128 + h]);
  p[2] = f2bf(W[(k0 + 2) * 128 + h]);
  p[3] = f2bf(W[(k0 + 3) * 128 + h]);
  *(ushort4v*)(WbT + linear) = p;
}

// ---------------------------------------------------------------------------
// Kernel 2: QKV projection — double-buffered LDS GEMM, BK=64, 1 barrier/iter.
// x staged as FP32 directly (no prep pass); converted to bf16 on LDS read.
// Tile 64M x 96N x 64K; grid = 128 rb x 4 cb = 512 blocks; 56 KB LDS.
// A rows: 16 chunks of 16B (4 floats), phys slot s=(c&8)|((c^row)&7).
// B rows: 8 chunks of 16B (8 bf16),  phys slot s=(c^row)&7.
// Q written pre-scaled by CSCALE. V written transposed (VT[b][h][t]).
// ---------------------------------------------------------------------------
__global__ __launch_bounds__(256) void qkv_proj(const float* __restrict__ x,
                                                const unsigned short* __restrict__ WbT,
                                                unsigned short* __restrict__ Qb,
                                                unsigned short* __restrict__ Kb,
                                                unsigned short* __restrict__ VT) {
  __shared__ float          Asf[2][64 * 64];  // 16 KB each
  __shared__ unsigned short Bs[2][96 * 64];   // 12 KB each

  const int tid  = threadIdx.x;
  const int wave = tid >> 6, lane = tid & 63;
  const int quad = lane >> 4, l15 = lane & 15;
  const int rb = blockIdx.x >> 2, cb = blockIdx.x & 3;
  const int gm0 = rb * 64, gn0 = cb * 96;
  const int wm = wave >> 1, wn = wave & 1;

  // staging geometry
  const int a_row4 = lane >> 4, a_slot = lane & 15;  // A: 4 rows/issue, 16 slots
  const int b_row8 = lane >> 3, b_slot = lane & 7;   // B: 8 rows/issue, 8 slots

  // B fragment read offsets (shorts)
  int boff[3][2];
#pragma unroll
  for (int nt = 0; nt < 3; ++nt) {
    const int r = wn * 48 + nt * 16 + l15;
#pragma unroll
    for (int ks = 0; ks < 2; ++ks)
      boff[nt][ks] = r * 64 + (((ks * 4 + quad) ^ r) & 7) * 8;
  }
  // A fragment read offsets (floats): two chunks per frag
  int aoff[2][2][2];
#pragma unroll
  for (int mt = 0; mt < 2; ++mt) {
    const int m = wm * 32 + mt * 16 + l15;
#pragma unroll
    for (int ks = 0; ks < 2; ++ks) {
      const int c0 = ks * 8 + quad * 2;
      const int s0 = (c0 & 8) | ((c0 ^ m) & 7);
      const int c1 = c0 + 1;
      const int s1 = (c1 & 8) | ((c1 ^ m) & 7);
      aoff[mt][ks][0] = m * 64 + s0 * 4;
      aoff[mt][ks][1] = m * 64 + s1 * 4;
    }
  }

  f32x4 acc[2][3];
  const f32x4 zero4 = {0.f, 0.f, 0.f, 0.f};
#pragma unroll
  for (int mt = 0; mt < 2; ++mt)
#pragma unroll
    for (int nt = 0; nt < 3; ++nt) acc[mt][nt] = zero4;

#define STAGE_QKV(buf, kb_)                                                        \
  {                                                                                \
    const int ko = (kb_) * 64;                                                     \
    _Pragma("unroll")                                                              \
    for (int q = 0; q < 4; ++q) {                                                  \
      const int row = wave * 16 + q * 4 + a_row4;                                  \
      const int c = (a_slot & 8) | ((a_slot ^ row) & 7);                           \
      gld16(x + (size_t)(gm0 + row) * C_ + ko + c * 4,                             \
            &Asf[buf][(wave * 16 + q * 4) * 64]);                                  \
    }                                                                              \
    _Pragma("unroll")                                                              \
    for (int q = 0; q < 3; ++q) {                                                  \
      const int row = wave * 24 + q * 8 + b_row8;                                  \
      gld16(WbT + (size_t)(gn0 + row) * C_ + ko + ((b_slot ^ row) & 7) * 8,        \
            &Bs[buf][(wave * 24 + q * 8) * 64]);                                   \
    }                                                                              \
  }

  STAGE_QKV(0, 0);

  for (int kb = 0; kb < 16; ++kb) {
    __syncthreads();                 // buf[kb&1] staged; prior reads of other done
    if (kb + 1 < 16) STAGE_QKV((kb + 1) & 1, kb + 1);
    const float* Ac = Asf[kb & 1];
    const unsigned short* Bc = Bs[kb & 1];
#pragma unroll
    for (int ks = 0; ks < 2; ++ks) {
      short8 a[2];
#pragma unroll
      for (int mt = 0; mt < 2; ++mt) {
        f32x4 va = *(const f32x4*)(Ac + aoff[mt][ks][0]);
        f32x4 vb = *(const f32x4*)(Ac + aoff[mt][ks][1]);
#pragma unroll
        for (int e = 0; e < 4; ++e) {
          a[mt][e]     = (short)f2bf(va[e]);
          a[mt][4 + e] = (short)f2bf(vb[e]);
        }
      }
      short8 b0 = *(const short8*)(Bc + boff[0][ks]);
      short8 b1 = *(const short8*)(Bc + boff[1][ks]);
      short8 b2 = *(const short8*)(Bc + boff[2][ks]);
      acc[0][0] = __builtin_amdgcn_mfma_f32_16x16x32_bf16(a[0], b0, acc[0][0], 0, 0, 0);
      acc[0][1] = __builtin_amdgcn_mfma_f32_16x16x32_bf16(a[0], b1, acc[0][1], 0, 0, 0);
      acc[0][2] = __builtin_amdgcn_mfma_f32_16x16x32_bf16(a[0], b2, acc[0][2], 0, 0, 0);
      acc[1][0] = __builtin_amdgcn_mfma_f32_16x16x32_bf16(a[1], b0, acc[1][0], 0, 0, 0);
      acc[1][1] = __builtin_amdgcn_mfma_f32_16x16x32_bf16(a[1], b1, acc[1][1], 0, 0, 0);
      acc[1][2] = __builtin_amdgcn_mfma_f32_16x16x32_bf16(a[1], b2, acc[1][2], 0, 0, 0);
    }
  }
#undef STAGE_QKV

  // epilogue: D[row=quad*4+r][col=l15] per 16x16 tile
#pragma unroll
  for (int mt = 0; mt < 2; ++mt) {
    const int row0 = gm0 + wm * 32 + mt * 16 + quad * 4;
#pragma unroll
    for (int nt = 0; nt < 3; ++nt) {
      const int colbase = gn0 + wn * 48 + nt * 16;
      const int col = colbase + l15;
      if (colbase < 128) {          // Q (pre-scaled)
#pragma unroll
        for (int r = 0; r < 4; ++r)
          Qb[(size_t)(row0 + r) * H_ + col] = f2bf(acc[mt][nt][r] * CSCALE);
      } else if (colbase < 256) {   // K
#pragma unroll
        for (int r = 0; r < 4; ++r)
          Kb[(size_t)(row0 + r) * H_ + (col - 128)] = f2bf(acc[mt][nt][r]);
      } else {                      // V, transposed
        const int h = col - 256;
        const int bidx = row0 >> 11;
        const int t0 = row0 & 2047;
        ushort4v pk;
        pk[0] = f2bf(acc[mt][nt][0]); pk[1] = f2bf(acc[mt][nt][1]);
        pk[2] = f2bf(acc[mt][nt][2]); pk[3] = f2bf(acc[mt][nt][3]);
        *(ushort4v*)(VT + (size_t)(bidx * H_ + h) * T_ + t0) = pk;
      }
    }
  }
}

// ---------------------------------------------------------------------------
// Kernel 3: flash attention stage 1. S^T formulation, K AND V double-buffered
// in LDS via swizzled gld16; one barrier per KV tile of 64. (Same as R5.)
// ---------------------------------------------------------------------------
__global__ __launch_bounds__(256, 2) void attn1(const unsigned short* __restrict__ Qb,
                                                const unsigned short* __restrict__ Kb,
                                                const unsigned short* __restrict__ VT,
                                                unsigned short* __restrict__ Opart,
                                                float* __restrict__ mpart,
                                                float* __restrict__ lpart,
                                                float* __restrict__ out) {
  __shared__ unsigned short Ks[2][64 * 128];   // 16 KB each; 16-slot rows
  __shared__ unsigned short Vs[2][128 * 64];   // 16 KB each; 8-slot rows
  __shared__ unsigned short Pls[4][16 * 72];   // 9 KB, per-wave P, pad 72
  __shared__ float Als[4][16];

  const int bid = blockIdx.x;
  const int b  = bid & 3;
  const int j  = (bid >> 2) & 31;
  const int ch = bid >> 7;
  if (ch * 4 > j) return;
  const int ntiles = min(4, j + 1 - ch * 4);

  const int tid  = threadIdx.x;
  const int wave = tid >> 6, lane = tid & 63;
  const int quad = lane >> 4, l15 = lane & 15;

  const unsigned short* qrow = Qb + (size_t)(b * T_ + j * 64 + wave * 16 + l15) * H_;
  short8 aq[4];
#pragma unroll
  for (int ks = 0; ks < 4; ++ks)
    aq[ks] = *(const short8*)(qrow + ks * 32 + quad * 8);

  const unsigned short* Kb_b = Kb + (size_t)(b * T_) * H_;
  const unsigned short* VT_b = VT + (size_t)(b * H_) * T_;

  const int k_row4 = lane >> 4, k_slot = lane & 15;
  const int v_row8 = lane >> 3, v_slot = lane & 7;

#define STAGE_KV(buf, kv0_)                                                        \
  {                                                                                \
    _Pragma("unroll")                                                              \
    for (int i = 0; i < 4; ++i) {                                                  \
      const int r = wave * 16 + i * 4 + k_row4;                                    \
      const int c2 = (k_slot & 8) | ((k_slot ^ r) & 7);                            \
      gld16(Kb_b + (size_t)((kv0_) + r) * H_ + c2 * 8,                             \
            &Ks[buf][(wave * 16 + i * 4) * 128]);                                  \
    }                                                                              \
    _Pragma("unroll")                                                              \
    for (int i = 0; i < 4; ++i) {                                                  \
      const int h = wave * 32 + i * 8 + v_row8;                                    \
      gld16(VT_b + (size_t)h * T_ + (kv0_) + ((v_slot ^ h) & 7) * 8,               \
            &Vs[buf][(wave * 32 + i * 8) * 64]);                                   \
    }                                                                              \
  }

  STAGE_KV(0, ch * 256);

  const f32x4 zero4 = {0.f, 0.f, 0.f, 0.f};
  f32x4 O[8];
#pragma unroll
  for (int nth = 0; nth < 8; ++nth) O[nth] = zero4;
  float m_ = NEG_BIG, l_ = 0.f;

  for (int t = 0; t < ntiles; ++t) {
    __syncthreads();
    const int kv0 = ch * 256 + t * 64;
    if (t + 1 < ntiles) STAGE_KV((t + 1) & 1, kv0 + 64);

    // ---- S^T = K . Q^T
    const unsigned short* kb = Ks[t & 1];
    f32x4 ST[4];
    ST[0] = zero4; ST[1] = zero4; ST[2] = zero4; ST[3] = zero4;
#pragma unroll
    for (int ntl = 0; ntl < 4; ++ntl) {
      const int kvr = ntl * 16 + l15;
#pragma unroll
      for (int ks = 0; ks < 4; ++ks) {
        const int c = ks * 4 + quad;
        const int slot = (c & 8) | ((c ^ kvr) & 7);
        short8 kf = *(const short8*)(kb + kvr * 128 + slot * 8);
        ST[ntl] = __builtin_amdgcn_mfma_f32_16x16x32_bf16(kf, aq[ks], ST[ntl], 0, 0, 0);
      }
    }

    // ---- causal mask (diagonal tile only)
    if (ch * 4 + t == j) {
      const int ql = j * 64 + wave * 16 + l15;
#pragma unroll
      for (int ntl = 0; ntl < 4; ++ntl)
#pragma unroll
        for (int r = 0; r < 4; ++r) {
          const int kl = kv0 + ntl * 16 + quad * 4 + r;
          if (kl > ql) ST[ntl][r] = NEG_BIG;
        }
    }

    // ---- softmax (per lane q=l15)
    float vmax = ST[0][0];
#pragma unroll
    for (int ntl = 0; ntl < 4; ++ntl)
#pragma unroll
      for (int r = 0; r < 4; ++r) vmax = fmaxf(vmax, ST[ntl][r]);
    vmax = fmaxf(vmax, __shfl_xor(vmax, 16));
    vmax = fmaxf(vmax, __shfl_xor(vmax, 32));
    const float mn = fmaxf(m_, vmax);
    const float alpha = __builtin_amdgcn_exp2f(m_ - mn);
    m_ = mn;
    float s = 0.f;
#pragma unroll
    for (int ntl = 0; ntl < 4; ++ntl)
#pragma unroll
      for (int r = 0; r < 4; ++r) {
        const float p = __builtin_amdgcn_exp2f(ST[ntl][r] - mn);
        ST[ntl][r] = p;
        s += p;
      }
    s += __shfl_xor(s, 16);
    s += __shfl_xor(s, 32);
    l_ = l_ * alpha + s;

    // ---- P -> LDS ([q][kv] layout)
#pragma unroll
    for (int ntl = 0; ntl < 4; ++ntl) {
      ushort4v pk;
      pk[0] = f2bf(ST[ntl][0]); pk[1] = f2bf(ST[ntl][1]);
      pk[2] = f2bf(ST[ntl][2]); pk[3] = f2bf(ST[ntl][3]);
      *(ushort4v*)(&Pls[wave][l15 * 72 + ntl * 16 + quad * 4]) = pk;
    }

    // ---- O rescale by alpha
    if (lane < 16) Als[wave][lane] = alpha;
    if (!__all(alpha == 1.f)) {
      f32x4 al4 = *(const f32x4*)&Als[wave][quad * 4];
#pragma unroll
      for (int nth = 0; nth < 8; ++nth)
#pragma unroll
        for (int r = 0; r < 4; ++r) O[nth][r] *= al4[r];
    }

    // ---- O += P . V
    const unsigned short* vb = Vs[t & 1];
    short8 ap0 = *(const short8*)(&Pls[wave][l15 * 72 + quad * 8]);
    short8 ap1 = *(const short8*)(&Pls[wave][l15 * 72 + 32 + quad * 8]);
#pragma unroll
    for (int nth = 0; nth < 8; ++nth) {
      const int h = nth * 16 + l15;
      short8 v0 = *(const short8*)(vb + h * 64 + ((quad ^ h) & 7) * 8);
      short8 v1 = *(const short8*)(vb + h * 64 + (((4 + quad) ^ h) & 7) * 8);
      O[nth] = __builtin_amdgcn_mfma_f32_16x16x32_bf16(ap0, v0, O[nth], 0, 0, 0);
      O[nth] = __builtin_amdgcn_mfma_f32_16x16x32_bf16(ap1, v1, O[nth], 0, 0, 0);
    }
  }
#undef STAGE_KV

  // ---- epilogue
  if ((j >> 2) == 0) {
    if (lane < 16) Als[wave][lane] = 1.0f / l_;
    f32x4 li4 = *(const f32x4*)&Als[wave][quad * 4];
    float* op = out + (size_t)(b * T_ + j * 64 + wave * 16) * H_;
#pragma unroll
    for (int nth = 0; nth < 8; ++nth)
#pragma unroll
      for (int r = 0; r < 4; ++r)
        op[(quad * 4 + r) * H_ + nth * 16 + l15] = O[nth][r] * li4[r];
  } else {
    const int pid = (b * 32 + j) * 8 + ch;
    unsigned short* po = Opart + (size_t)(pid * 64 + wave * 16) * H_;
#pragma unroll
    for (int nth = 0; nth < 8; ++nth)
#pragma unroll
      for (int r = 0; r < 4; ++r)
        po[(quad * 4 + r) * H_ + nth * 16 + l15] = f2bf(O[nth][r]);
    if (lane < 16) {
      mpart[pid * 64 + wave * 16 + lane] = m_;
      lpart[pid * 64 + wave * 16 + lane] = l_;
    }
  }
}

// ---------------------------------------------------------------------------
// Kernel 4: stage-2 combine for j >= 4. Grid = 4 b x 28 j = 112 blocks.
// ---------------------------------------------------------------------------
__global__ __launch_bounds__(256) void attn2(const unsigned short* __restrict__ Opart,
                                             const float* __restrict__ mpart,
                                             const float* __restrict__ lpart,
                                             float* __restrict__ out) {
  const int b = blockIdx.x & 3;
  const int j = 4 + (blockIdx.x >> 2);
  const int nch = (j >> 2) + 1;       // 2..8
  const int tid = threadIdx.x;
  const int qh = tid >> 4;            // 0..15
  const int h0 = (tid & 15) * 8;
  const int pbase = (b * 32 + j) * 8;

#pragma unroll
  for (int i = 0; i < 4; ++i) {
    const int q = qh + i * 16;        // 0..63
    float m_fin = NEG_BIG;
    for (int ch = 0; ch < nch; ++ch)
      m_fin = fmaxf(m_fin, mpart[(pbase + ch) * 64 + q]);
    float lf = 0.f;
    float o[8];
#pragma unroll
    for (int c = 0; c < 8; ++c) o[c] = 0.f;
    for (int ch = 0; ch < nch; ++ch) {
      const int pid = pbase + ch;
      const float sc = __builtin_amdgcn_exp2f(mpart[pid * 64 + q] - m_fin);
      lf += sc * lpart[pid * 64 + q];
      ushort8v pv = *(const ushort8v*)(Opart + (size_t)(pid * 64 + q) * H_ + h0);
#pragma unroll
      for (int c = 0; c < 8; ++c) o[c] += sc * bf2f(pv[c]);
    }
    const float inv = 1.0f / lf;
    float* op = out + (size_t)(b * T_ + j * 64 + q) * H_ + h0;
    f32x4 v0 = {o[0] * inv, o[1] * inv, o[2] * inv, o[3] * inv};
    f32x4 v1 = {o[4] * inv, o[5] * inv, o[6] * inv, o[7] * inv};
    *(f32x4*)(op) = v0;
    *(f32x4*)(op + 4) = v1;
  }
}

// ---------------------------------------------------------------------------
extern "C" void kernel_launch(void* const* d_in, const int* in_sizes, int n_in,
                              void* d_out, int out_size, void* d_ws, size_t ws_size,
                              hipStream_t stream) {
  const float* x  = (const float*)d_in[0];
  const float* Wq = (const float*)d_in[1];
  const float* Wk = (const float*)d_in[2];
  const float* Wv = (const float*)d_in[3];
  float* out = (float*)d_out;

  char* ws = (char*)d_ws;
  unsigned short* WbT = (unsigned short*)(ws);              // [0, 768 KB)
  unsigned short* Qb  = (unsigned short*)(ws + 1048576);    // [1 MB, 3 MB)
  unsigned short* Kb  = (unsigned short*)(ws + 3145728);    // [3 MB, 5 MB)
  unsigned short* VT  = (unsigned short*)(ws + 5242880);    // [5 MB, 7 MB)
  unsigned short* Opart = (unsigned short*)(ws + 8388608);  // [8 MB, 24 MB)
  float* mpart = (float*)(ws + 25165824);                   // [24 MB, +256 KB)
  float* lpart = (float*)(ws + 25427968);                   // +256 KB

  prep_w<<<dim3(384), dim3(256), 0, stream>>>(Wq, Wk, Wv, WbT);
  qkv_proj<<<dim3(512), dim3(256), 0, stream>>>(x, WbT, Qb, Kb, VT);
  attn1<<<dim3(1024), dim3(256), 0, stream>>>(Qb, Kb, VT, Opart, mpart, lpart, out);
  attn2<<<dim3(112), dim3(256), 0, stream>>>(Opart, mpart, lpart, out);
}